// Round 10
// baseline (1960.476 us; speedup 1.0000x reference)
//
#include <hip/hip_runtime.h>
#include <math.h>

#define BB 128
#define TT 32
#define DDIM 64
#define VV 4096
#define SS 32
#define RR 8
#define NT 512
#define SMP 65   // padded leading dim for s_mem

typedef unsigned short u16;
typedef unsigned int u32;
typedef _Float16 h2 __attribute__((ext_vector_type(2)));

__device__ __forceinline__ h2 bch(u32 u){ union { u32 u; h2 h; } v; v.u = u; return v.h; }

__device__ __forceinline__ float fdot2f(u32 a, u32 b, float acc){
#if __has_builtin(__builtin_amdgcn_fdot2)
  return __builtin_amdgcn_fdot2(bch(a), bch(b), acc, false);
#else
  h2 x = bch(a), y = bch(b);
  return acc + (float)x[0] * (float)y[0] + (float)x[1] * (float)y[1];
#endif
}

__device__ __forceinline__ u32 packh2(float a, float b){
  union { _Float16 h[2]; u32 u; } p;
  p.h[0] = (_Float16)a; p.h[1] = (_Float16)b;
  return p.u;
}

__device__ __forceinline__ void bar(){ __syncthreads(); }

// ---------------- K0a: pack vq_emb into lane-coalesced f16 tiles ----------------
// vqT uint4 index: ((c0*16 + dc8)*64 + l), code c = c0*64+l, dims dc8*8..dc8*8+7 (8 f16)
__global__ __launch_bounds__(256) void k_pack(const float* __restrict__ vq, u32* __restrict__ vqT){
  int gid = blockIdx.x * 256 + threadIdx.x;     // 65536 entries
  int l   = gid & 63;
  int dc8 = (gid >> 6) & 15;
  int c0  = gid >> 10;
  int c   = (c0 << 6) + l;
  const float* s = vq + c * 128 + dc8 * 8;
  uint4 o;
  o.x = packh2(s[0], s[1]);
  o.y = packh2(s[2], s[3]);
  o.z = packh2(s[4], s[5]);
  o.w = packh2(s[6], s[7]);
  ((uint4*)vqT)[gid] = o;
}

// ---------------- K0b: per-code squared norm (exact f32) ----------------
__global__ __launch_bounds__(256) void k_vqsq(const float* __restrict__ vq, float* __restrict__ vqsq){
  int c = blockIdx.x * 256 + threadIdx.x;
  float s = 0.f;
  for (int d = 0; d < 128; d++){ float v = vq[c * 128 + d]; s = fmaf(v, v, s); }
  vqsq[c] = s;
}

// 8x uint4 global load batch (one half-k of the VQ tile walk)
__device__ __forceinline__ void load8(uint4 (&U)[8], const uint4* vp){
  #pragma unroll
  for (int j = 0; j < 8; j++) U[j] = vp[j * 64];
}

// 32 fdot2 on one half-k; F read from LDS (uniform addr -> broadcast, no conflict).
// Accumulation grouping/order identical to the R5/R6 4-acc loop (bit-identical).
__device__ __forceinline__ void dot8L(const uint4 (&U)[8], const uint4* Fl, int off,
                                      float& a0, float& a1, float& a2, float& a3){
  #pragma unroll
  for (int j = 0; j < 8; j += 4){
    uint4 f0 = Fl[off + j + 0];
    uint4 f1 = Fl[off + j + 1];
    uint4 f2 = Fl[off + j + 2];
    uint4 f3 = Fl[off + j + 3];
    a0 = fdot2f(U[j+0].x, f0.x, a0); a0 = fdot2f(U[j+0].y, f0.y, a0);
    a0 = fdot2f(U[j+0].z, f0.z, a0); a0 = fdot2f(U[j+0].w, f0.w, a0);
    a1 = fdot2f(U[j+1].x, f1.x, a1); a1 = fdot2f(U[j+1].y, f1.y, a1);
    a1 = fdot2f(U[j+1].z, f1.z, a1); a1 = fdot2f(U[j+1].w, f1.w, a1);
    a2 = fdot2f(U[j+2].x, f2.x, a2); a2 = fdot2f(U[j+2].y, f2.y, a2);
    a2 = fdot2f(U[j+2].z, f2.z, a2); a2 = fdot2f(U[j+2].w, f2.w, a2);
    a3 = fdot2f(U[j+3].x, f3.x, a3); a3 = fdot2f(U[j+3].y, f3.y, a3);
    a3 = fdot2f(U[j+3].z, f3.z, a3); a3 = fdot2f(U[j+3].w, f3.w, a3);
  }
}

// ---------------- K1: the full recurrence, one block per batch row ----------------
// R10 = R9 resubmitted verbatim (R9's bench died with a containerless infra
// signature identical to R1's; the kernel contains no plausible hang construct —
// uniform barriers, static bounds, no inline asm). Delta vs R5 (passed, 450us):
// pipelined VQ loop fitting the 128-VGPR cap by reading F via LDS broadcast
// instead of 64 registers; half-k double buffer Ua/Ub (R2-proven order).
__global__ __launch_bounds__(NT) void k_recur(
    const int* __restrict__ x_seq, const float* __restrict__ enc_emb,
    const float* __restrict__ vq_emb, const u32* __restrict__ vqT,
    const float* __restrict__ vq_sq,
    const float* __restrict__ nrg, const float* __restrict__ nrb,
    const float* __restrict__ nig, const float* __restrict__ nib,
    const float* __restrict__ proj_w, const float* __restrict__ proj_b,
    const float* __restrict__ mgw, const float* __restrict__ mgb,
    const float* __restrict__ arb_w, const float* __restrict__ arb_b,
    const float* __restrict__ hb, const float* __restrict__ ig,
    float* __restrict__ gwout,
    int* __restrict__ idxbuf, int* __restrict__ rstop_g, float* __restrict__ accs,
    float* __restrict__ out_mem)
{
  const int b = blockIdx.x;
  const int tid = threadIdx.x;
  const int lane = tid & 63;
  const int wave = tid >> 6;

  __shared__ __align__(16) float s_gw[128];     // state (own-element updates only)
  __shared__ __align__(16) float s_flat[128];
  __shared__ __align__(16) u32   s_flath[64];   // f16 copy of s_flat (64 half2)
  __shared__ __align__(16) float s_c[128];      // committed state copy (stable for PH / wg)
  __shared__ __align__(16) float s_zq[128];     // selected code row (wave 1, MV phase)
  __shared__ __align__(16) float s_enext[128];  // next-t embedding row (wave 3, MV r=0)
  __shared__ float s_mem[2][SS][SMP];           // padded: no stride-64 conflicts
  __shared__ __align__(16) float s_mv[12][DDIM];// s_mv[2*w2+half]: xhalf @ W(p,wsel)
  __shared__ float s_sim[SS];
  __shared__ float s_red[8];                    // 0: vq_loss, 4..6: arb logits
  __shared__ float s_cand[8];
  __shared__ int   s_candi[8];

  for (int i = tid; i < 128; i += NT) s_gw[i] = 0.f;
  for (int i = tid; i < 2 * SS * SMP; i += NT) ((float*)s_mem)[i] = 0.f;
  // first embedding row staged before the loop
  if (tid < 128) s_enext[tid] = enc_emb[x_seq[b * TT] * 128 + tid];
  __syncthreads();

  const float alpha = 1.f / (1.f + expf(-ig[0]));
  float bias_h; { float x = hb[0]; bias_h = log1pf(expf(x)); }
  int head = 0;
  float prev_ang = 0.f;   // wave 2 only
  float acc_ph = 0.f;     // wave 2 only

  // per-lane proj_b preloads (layout (3,2,64)): [(p*2+ri)*64 + lane]
  const float pb0r = proj_b[lane],        pb0i = proj_b[64 + lane];
  const float pb1r = proj_b[128 + lane],  pb1i = proj_b[192 + lane];
  const float pb2r = proj_b[256 + lane],  pb2i = proj_b[320 + lane];

  const uint4* vqT4 = (const uint4*)vqT;

  #pragma unroll 1
  for (int t = 0; t < TT; t++){
    // ---- E: embedding blend from staged row (own elements only)
    if (tid < 128){
      s_gw[tid] = alpha * s_gw[tid] + (1.f - alpha) * s_enext[tid];
    }
    bar();                                  // B0: s_gw blended, visible
    if (wave == 2) prev_ang = atan2f(s_gw[64 + lane], s_gw[lane]);

    float vl_last = 0.f;
    if (wave == 2) acc_ph = 0.f;
    int rst = 0;
    bool stop = false;

    #pragma unroll 1
    for (int r = 0; r < RR; r++){
      // ---- LN halves -> s_flat (f32) + s_flath (f16 pairs)  [waves 0,1]
      if (wave < 2){
        float x = s_gw[wave * 64 + lane];   // own element (written by this thread)
        float mu = x;
        #pragma unroll
        for (int m = 1; m < 64; m <<= 1) mu += __shfl_xor(mu, m);
        mu *= (1.f / 64.f);
        float dxl = x - mu;
        float vv = dxl * dxl;
        #pragma unroll
        for (int m = 1; m < 64; m <<= 1) vv += __shfl_xor(vv, m);
        vv *= (1.f / 64.f);
        float rs = 1.f / sqrtf(vv + 1e-5f);
        const float* g  = wave ? nig : nrg;
        const float* bb = wave ? nib : nrb;
        float fv = dxl * rs * g[lane] + bb[lane];
        s_flat[wave * 64 + lane] = fv;
        float pv = __shfl_xor(fv, 1);
        if ((lane & 1) == 0)
          s_flath[(wave * 64 + lane) >> 1] = packh2(fv, pv);
      }
      bar();                                // B1: flat ready

      // ---- VQ nearest-code search: half-k double buffer (Ua/Ub), F from LDS
      //      broadcast reads, prefetched vq_sq. Fits 128 VGPRs (no F registers).
      {
        const uint4* Fl = (const uint4*)s_flath;  // uniform across lanes -> broadcast
        uint4 Ua[8], Ub[8];
        load8(Ua, vqT4 + (wave * 16) * 64 + lane);
        load8(Ub, vqT4 + (wave * 16 + 8) * 64 + lane);
        float Q[8];
        #pragma unroll
        for (int k = 0; k < 8; k++) Q[k] = vq_sq[((wave + 8 * k) << 6) + lane];

        float bsc = 3.4e38f; int bidx = 0;
        #pragma unroll
        for (int k = 0; k < 8; k++){
          float a0 = 0.f, a1 = 0.f, a2 = 0.f, a3 = 0.f;
          dot8L(Ua, Fl, 0, a0, a1, a2, a3);
          if (k < 7) load8(Ua, vqT4 + ((wave + 8 * (k + 1)) * 16) * 64 + lane);
          dot8L(Ub, Fl, 8, a0, a1, a2, a3);
          if (k < 7) load8(Ub, vqT4 + ((wave + 8 * (k + 1)) * 16 + 8) * 64 + lane);
          float dot = (a0 + a1) + (a2 + a3);
          int c = ((wave + 8 * k) << 6) + lane;
          float sc = Q[k] - 2.f * dot;
          if (sc < bsc || (sc == bsc && c < bidx)){ bsc = sc; bidx = c; }
        }
        #pragma unroll
        for (int m = 1; m < 64; m <<= 1){
          float os = __shfl_xor(bsc, m);
          int   oi = __shfl_xor(bidx, m);
          if (os < bsc || (os == bsc && oi < bidx)){ bsc = os; bidx = oi; }
        }
        if (lane == 0){ s_cand[wave] = bsc; s_candi[wave] = bidx; }
      }
      bar();                                // B2: candidates ready

      // ---- MV phase: role-split.
      //   waves 2..7: one proj_w matrix each, BOTH x-half dots (halves W traffic)
      //   wave 3 additionally stages next-t enc row at r==0
      //   wave 0: sim + softmax
      //   wave 1: imin reduce + arb + vq_loss + zq stash + idx write
      if (wave >= 2){
        if (wave == 3 && r == 0 && t + 1 < TT){
          int xn = x_seq[b * TT + t + 1];
          s_enext[lane]      = enc_emb[xn * 128 + lane];
          s_enext[64 + lane] = enc_emb[xn * 128 + 64 + lane];
        }
        const int w2 = wave - 2;            // 0..5 -> (p, wsel)
        const int p = w2 >> 1, wsel = w2 & 1;
        const float* W = proj_w + ((p * 2 + wsel) << 12);
        float a0=0.f,a1=0.f,a2=0.f,a3=0.f;  // x_low (dims 0..63)
        float b0=0.f,b1=0.f,b2=0.f,b3=0.f;  // x_high (dims 64..127)
        #pragma unroll
        for (int i = 0; i < 64; i += 4){
          float4 xr4 = *(const float4*)&s_flat[i];
          float4 xi4 = *(const float4*)&s_flat[64 + i];
          float w0 = W[(i + 0) * 64 + lane];
          float w1 = W[(i + 1) * 64 + lane];
          float w2v= W[(i + 2) * 64 + lane];
          float w3 = W[(i + 3) * 64 + lane];
          a0 = fmaf(xr4.x, w0, a0); a1 = fmaf(xr4.y, w1, a1);
          a2 = fmaf(xr4.z, w2v, a2); a3 = fmaf(xr4.w, w3, a3);
          b0 = fmaf(xi4.x, w0, b0); b1 = fmaf(xi4.y, w1, b1);
          b2 = fmaf(xi4.z, w2v, b2); b3 = fmaf(xi4.w, w3, b3);
        }
        s_mv[w2 * 2 + 0][lane] = (a0 + a1) + (a2 + a3);   // x_low  @ W
        s_mv[w2 * 2 + 1][lane] = (b0 + b1) + (b2 + b3);   // x_high @ W
      } else if (wave == 0){
        // sim over 32 slots (lane<32: dims 0-63, lane>=32: dims 64-127) + softmax
        const int s2 = lane & 31, h = lane >> 5;
        const float* mrow = &s_mem[h][s2][0];
        const float* fx = s_flat + h * 64;
        float a0=0.f,a1=0.f,a2=0.f,a3=0.f;
        #pragma unroll
        for (int d = 0; d < 64; d += 4){
          a0 = fmaf(mrow[d + 0], fx[d + 0], a0);
          a1 = fmaf(mrow[d + 1], fx[d + 1], a1);
          a2 = fmaf(mrow[d + 2], fx[d + 2], a2);
          a3 = fmaf(mrow[d + 3], fx[d + 3], a3);
        }
        float p = (a0 + a1) + (a2 + a3);
        p += __shfl_xor(p, 32);             // full 128-dim sim, dup in both halves
        float mx = p;
        #pragma unroll
        for (int m = 1; m < 32; m <<= 1) mx = fmaxf(mx, __shfl_xor(mx, m));
        float e = expf(p - mx);
        float sm = e;
        #pragma unroll
        for (int m = 1; m < 32; m <<= 1) sm += __shfl_xor(sm, m);
        if (lane < 32) s_sim[lane] = e / sm;
      } else {
        // wave 1: imin reduce + arbiter logits + vq_loss + zq stash + idx write
        float bs = s_cand[0]; int bi = s_candi[0];
        #pragma unroll
        for (int w = 1; w < 8; w++){
          float os = s_cand[w]; int oi = s_candi[w];
          if (os < bs || (os == bs && oi < bi)){ bs = os; bi = oi; }
        }
        int imin = __builtin_amdgcn_readfirstlane(bi);
        float f0 = s_flat[lane], f1 = s_flat[64 + lane];
        float p0 = fmaf(f0, arb_w[lane * 3 + 0], f1 * arb_w[(64 + lane) * 3 + 0]);
        float p1 = fmaf(f0, arb_w[lane * 3 + 1], f1 * arb_w[(64 + lane) * 3 + 1]);
        float p2 = fmaf(f0, arb_w[lane * 3 + 2], f1 * arb_w[(64 + lane) * 3 + 2]);
        float z0 = vq_emb[imin * 128 + lane];
        float z1 = vq_emb[imin * 128 + 64 + lane];
        s_zq[lane]      = z0;
        s_zq[64 + lane] = z1;
        float d0 = z0 - f0, d1 = z1 - f1;
        float sq = d0 * d0 + d1 * d1;
        #pragma unroll
        for (int m = 1; m < 64; m <<= 1){
          p0 += __shfl_xor(p0, m); p1 += __shfl_xor(p1, m);
          p2 += __shfl_xor(p2, m); sq += __shfl_xor(sq, m);
        }
        if (lane == 0){
          s_red[4] = p0 + arb_b[0];
          s_red[5] = p1 + arb_b[1];
          s_red[6] = p2 + arb_b[2];
          s_red[0] = 1.25f * sq * (1.f / 128.f);
          idxbuf[(b * TT + t) * RR + r] = imin;
        }
      }
      bar();                                // B3: mv, sim, arb, vq_loss, zq ready

      float vl = s_red[0];
      stop = (bias_h - vl) > 0.f;           // bit-identical in every thread -> uniform
      vl_last = vl; rst = r;

      // ---- CAND: per-lane q/k/w combine, gate reduce, memory read, gates softmax,
      //      candidate, commit
      if (tid < 128){
        float qr = s_mv[0][lane] - s_mv[3][lane] + pb0r - pb0i;
        float qi = s_mv[1][lane] + s_mv[2][lane] + pb0r + pb0i;
        float kr = s_mv[4][lane] - s_mv[7][lane] + pb1r - pb1i;
        float ki = s_mv[5][lane] + s_mv[6][lane] + pb1r + pb1i;
        float g = fmaf(qr, kr, qi * ki);
        #pragma unroll
        for (int m = 1; m < 64; m <<= 1) g += __shfl_xor(g, m);
        float gate = 1.f / (1.f + expf(-g));
        const int h = wave, j = lane;
        float m_reg = 0.f;
        #pragma unroll 8
        for (int s2 = 0; s2 < 32; s2++)
          m_reg = fmaf(s_sim[s2], s_mem[h][s2][j], m_reg);
        float l0 = s_red[4], l1 = s_red[5], l2 = s_red[6];
        float mx = fmaxf(l0, fmaxf(l1, l2));
        float e0 = expf(l0 - mx), e1 = expf(l1 - mx), e2 = expf(l2 - mx);
        float inv = 1.f / (e0 + e1 + e2);
        float zq = s_zq[tid];               // LDS (stashed by wave 1 in MV)
        float wv = h ? (s_mv[9][j] + s_mv[10][j] + pb2r + pb2i)
                     : (s_mv[8][j] - s_mv[11][j] + pb2r - pb2i);
        float u = (e0 * inv) * (gate * wv) + (e1 * inv) * m_reg + (e2 * inv) * zq;
        float cv = 0.6f * s_flat[tid] + 0.4f * u;
        s_c[tid]  = cv;       // stable copy for PH / wg readers
        s_gw[tid] = cv;       // state commit
      }
      bar();                                // B4: s_c ready

      // ---- PH: phase difference (wave 2 — does not serialize with next-r LN)
      if (wave == 2){
        float ang = atan2f(s_c[64 + lane], s_c[lane]);
        float df = fabsf(ang - prev_ang);
        df = fminf(df, 6.28318530717958647692f - df);
        prev_ang = ang;
        #pragma unroll
        for (int m = 1; m < 64; m <<= 1) df += __shfl_xor(df, m);
        acc_ph += df * (1.f / 64.f);
        if ((stop || r == RR - 1) && lane == 0)
          accs[(b * TT + t) * 4 + 2] = acc_ph;
      }
      if (stop) break;
    } // r

    // ---- post-t: output, memory-gate (redundant in waves 0,1), memory update
    float pond = 0.01f * (float)(rst + 1);
    if (tid < 128) gwout[(b * TT + t) * 128 + tid] = s_gw[tid];   // own value
    head = (head + SS - 1) & (SS - 1);
    if (wave < 2){
      float p = fmaf(s_c[lane], mgw[lane], s_c[64 + lane] * mgw[64 + lane]);
      #pragma unroll
      for (int m = 1; m < 64; m <<= 1) p += __shfl_xor(p, m);
      float wg = 1.f / (1.f + expf(-(p + mgb[0])));
      const int h = wave, d0 = lane;
      float old = s_mem[h][head][d0];
      s_mem[h][head][d0] = wg * s_c[h * 64 + d0] + (1.f - wg) * old;
    }
    if (tid == 0){
      int o = b * TT + t;
      rstop_g[o] = rst;
      accs[o * 4 + 0] = vl_last;
      accs[o * 4 + 1] = pond;
    }
    // ordering to next t: s_gw/E own-element; s_enext write (wave3, MV r=0) vs E read
    // separated by B0..B2; s_c next write after next B3; s_mem next read after next B2.
  } // t

  bar();
  for (int i = tid; i < SS * DDIM; i += NT){
    int s2 = i >> 6, d0 = i & 63;
    int ph = (head + s2) & (SS - 1);
    out_mem[b * SS * DDIM + i] = s_mem[0][ph][d0];
    out_mem[BB * SS * DDIM + b * SS * DDIM + i] = s_mem[1][ph][d0];
  }
}

// ---------------- Kmax: per-timestep max r_stop + zero stats accumulators ----------------
__global__ __launch_bounds__(256) void k_max(const int* __restrict__ rstop_g,
                                             int* __restrict__ maxr,
                                             float* __restrict__ out_stats){
  __shared__ int sm[8][TT];
  int tid = threadIdx.x;
  int t = tid & 31, q = tid >> 5;           // 8 groups x 16 b's each
  int mx = 0;
  for (int b = q * 16; b < q * 16 + 16; b++) mx = max(mx, rstop_g[b * TT + t]);
  sm[q][t] = mx;
  __syncthreads();
  if (tid < TT){
    int m = sm[0][tid];
    #pragma unroll
    for (int qq = 1; qq < 8; qq++) m = max(m, sm[qq][tid]);
    maxr[tid] = m;
  } else if (tid >= 64 && tid < 69){
    out_stats[tid - 64] = 0.f;              // zeroed every launch, before k_stats
  }
}

// ---------------- K1b: fill frozen tail idx (cold path) ----------------
// Recomputes LN(gwout) with the identical shuffle sequence the hot path uses.
__global__ __launch_bounds__(256) void k_tail(
    const u32* __restrict__ vqT, const float* __restrict__ vq_sq,
    const float* __restrict__ gwout, const int* __restrict__ rstop_g,
    const int* __restrict__ maxr, int* __restrict__ idxbuf,
    const float* __restrict__ nrg, const float* __restrict__ nrb,
    const float* __restrict__ nig, const float* __restrict__ nib)
{
  int o = blockIdx.x;               // b*TT + t
  int t = o & (TT - 1);
  int rs = rstop_g[o];
  if (rs >= maxr[t]) return;
  __shared__ __align__(16) u32 sfh[64];
  __shared__ float s_cand[4];
  __shared__ int   s_candi[4];
  int tid = threadIdx.x, lane = tid & 63, wave = tid >> 6;
  if (wave < 2){
    float x = gwout[o * 128 + wave * 64 + lane];
    float mu = x;
    #pragma unroll
    for (int m = 1; m < 64; m <<= 1) mu += __shfl_xor(mu, m);
    mu *= (1.f / 64.f);
    float dxl = x - mu;
    float vv = dxl * dxl;
    #pragma unroll
    for (int m = 1; m < 64; m <<= 1) vv += __shfl_xor(vv, m);
    vv *= (1.f / 64.f);
    float rsn = 1.f / sqrtf(vv + 1e-5f);
    const float* g  = wave ? nig : nrg;
    const float* bb = wave ? nib : nrb;
    float fv = dxl * rsn * g[lane] + bb[lane];
    float pv = __shfl_xor(fv, 1);
    if ((lane & 1) == 0) sfh[(wave * 64 + lane) >> 1] = packh2(fv, pv);
  }
  __syncthreads();
  uint4 F[16];
  {
    const uint4* sfh4 = (const uint4*)sfh;
    #pragma unroll
    for (int i = 0; i < 16; i++) F[i] = sfh4[i];
  }
  float bsc = 3.4e38f; int bidx = 0;
  #pragma unroll 1
  for (int k = 0; k < 16; k++){
    int c0 = wave + 4 * k;
    const uint4* vp = ((const uint4*)vqT) + (c0 * 16) * 64 + lane;
    uint4 U[16];
    #pragma unroll
    for (int dc8 = 0; dc8 < 16; dc8++) U[dc8] = vp[dc8 * 64];
    float dot = 0.f;
    #pragma unroll
    for (int dc8 = 0; dc8 < 16; dc8++){
      dot = fdot2f(U[dc8].x, F[dc8].x, dot);
      dot = fdot2f(U[dc8].y, F[dc8].y, dot);
      dot = fdot2f(U[dc8].z, F[dc8].z, dot);
      dot = fdot2f(U[dc8].w, F[dc8].w, dot);
    }
    int c = c0 * 64 + lane;
    float sc = vq_sq[c] - 2.f * dot;
    if (sc < bsc || (sc == bsc && c < bidx)){ bsc = sc; bidx = c; }
  }
  #pragma unroll
  for (int m = 1; m < 64; m <<= 1){
    float os = __shfl_xor(bsc, m);
    int   oi = __shfl_xor(bidx, m);
    if (os < bsc || (os == bsc && oi < bidx)){ bsc = os; bidx = oi; }
  }
  if (lane == 0){ s_cand[wave] = bsc; s_candi[wave] = bidx; }
  __syncthreads();
  if (tid == 0){
    float bs = s_cand[0]; int bi = s_candi[0];
    for (int w = 1; w < 4; w++){
      float os = s_cand[w]; int oi = s_candi[w];
      if (os < bs || (os == bs && oi < bi)){ bs = os; bi = oi; }
    }
    for (int r = rs + 1; r < RR; r++) idxbuf[o * RR + r] = bi;
  }
}

// ---------------- K2: entropy/perplexity + final stats (32 blocks, one per t) ----------------
// out_stats zeroed by k_max (stream-ordered earlier); partial means accumulated
// via atomicAdd (f32 reorder error ~1e-7, far under tolerance).
__global__ __launch_bounds__(512) void k_stats(
    const int* __restrict__ idxbuf, const int* __restrict__ rstop_g,
    const float* __restrict__ accs, const int* __restrict__ maxr,
    float* __restrict__ out_stats)
{
  __shared__ int   s_vals[8][128];
  __shared__ float s_ent2[RR];
  __shared__ float s_part[8][5];
  const int t = blockIdx.x;
  int tid = threadIdx.x, lane = tid & 63, wave = tid >> 6;
  int mr = maxr[t];
  int r = wave;                       // 8 waves <-> 8 r's
  if (r <= mr){
    int v1 = idxbuf[(lane * TT + t) * RR + r];
    int v2 = idxbuf[((64 + lane) * TT + t) * RR + r];
    s_vals[wave][lane]      = v1;
    s_vals[wave][64 + lane] = v2;     // same-wave LDS RAW: ordered by lgkmcnt
    int c1 = 0, c2 = 0;
    for (int j = 0; j < 128; j++){
      int v = s_vals[wave][j];
      c1 += (v == v1); c2 += (v == v2);
    }
    float contrib = -(logf((float)c1 * (1.f / 128.f) + 1e-10f)
                    + logf((float)c2 * (1.f / 128.f) + 1e-10f)) * (1.f / 128.f);
    #pragma unroll
    for (int m = 1; m < 64; m <<= 1) contrib += __shfl_xor(contrib, m);
    if (lane == 0) s_ent2[r] = contrib;
  }
  __syncthreads();

  float sv = 0.f, sp = 0.f, se = 0.f, sn = 0.f, sh = 0.f;
  if (tid < BB){
    int o = tid * TT + t;             // one b per thread
    int rs = rstop_g[o];
    float ent = s_ent2[rs];
    se = ent;
    sp = expf(ent);
    sv = accs[o * 4 + 0];
    sn = accs[o * 4 + 1];
    sh = accs[o * 4 + 2];
  }
  #pragma unroll
  for (int m = 1; m < 64; m <<= 1){
    sv += __shfl_xor(sv, m); sp += __shfl_xor(sp, m); se += __shfl_xor(se, m);
    sn += __shfl_xor(sn, m); sh += __shfl_xor(sh, m);
  }
  if (lane == 0){
    s_part[wave][0] = sv; s_part[wave][1] = sp; s_part[wave][2] = se;
    s_part[wave][3] = sn; s_part[wave][4] = sh;
  }
  __syncthreads();
  if (tid == 0){
    float a[5] = {0.f, 0.f, 0.f, 0.f, 0.f};
    for (int w = 0; w < 8; w++)
      for (int j = 0; j < 5; j++) a[j] += s_part[w][j];
    const float inv = 1.f / (float)(BB * TT);
    for (int j = 0; j < 5; j++) atomicAdd(&out_stats[j], a[j] * inv);
  }
}

// ---------------- K3: decoder GEMM  logits = flat_out @ dec_w + dec_b ----------------
__global__ __launch_bounds__(256) void k_dec(
    const float* __restrict__ gwout, const float* __restrict__ dec_w,
    const float* __restrict__ dec_b, float* __restrict__ out)
{
  __shared__ float At[32][128];
  int tid = threadIdx.x;
  int row0 = blockIdx.y * 32;
  int col0 = blockIdx.x * 256;
  {
    const float4* src = (const float4*)(gwout + row0 * 128);
    float4* dst = (float4*)&At[0][0];
    for (int i = tid; i < 1024; i += 256) dst[i] = src[i];
  }
  __syncthreads();
  int v = col0 + tid;
  float acc[32];
  #pragma unroll
  for (int r2 = 0; r2 < 32; r2++) acc[r2] = 0.f;
  for (int k = 0; k < 128; k += 4){
    float w0 = dec_w[(k + 0) * 4096 + v];
    float w1 = dec_w[(k + 1) * 4096 + v];
    float w2 = dec_w[(k + 2) * 4096 + v];
    float w3 = dec_w[(k + 3) * 4096 + v];
    #pragma unroll
    for (int r2 = 0; r2 < 32; r2++){
      float4 a = *(const float4*)&At[r2][k];
      acc[r2] = fmaf(a.x, w0, fmaf(a.y, w1, fmaf(a.z, w2, fmaf(a.w, w3, acc[r2]))));
    }
  }
  float bv = dec_b[v];
  for (int r2 = 0; r2 < 32; r2++)
    out[(row0 + r2) * 4096 + v] = acc[r2] + bv;
}

extern "C" void kernel_launch(void* const* d_in, const int* in_sizes, int n_in,
                              void* d_out, int out_size, void* d_ws, size_t ws_size,
                              hipStream_t stream){
  const int*   x_seq   = (const int*)  d_in[0];
  const float* enc_emb = (const float*)d_in[1];
  const float* vq_emb  = (const float*)d_in[2];
  const float* nrg     = (const float*)d_in[3];
  const float* nrb     = (const float*)d_in[4];
  const float* nig     = (const float*)d_in[5];
  const float* nib     = (const float*)d_in[6];
  const float* proj_w  = (const float*)d_in[7];
  const float* proj_b  = (const float*)d_in[8];
  const float* mgw     = (const float*)d_in[9];
  const float* mgb     = (const float*)d_in[10];
  const float* arb_w   = (const float*)d_in[11];
  const float* arb_b   = (const float*)d_in[12];
  const float* dec_w   = (const float*)d_in[13];
  const float* dec_b   = (const float*)d_in[14];
  const float* hb      = (const float*)d_in[15];
  const float* ig      = (const float*)d_in[16];

  char* ws = (char*)d_ws;
  u32*   vqT    = (u32*)  (ws + 0);            // 1,048,576 B (f16 tiles)
  float* vqsq   = (float*)(ws + 2097152);      //    16,384 B
  float* gwout  = (float*)(ws + 2113536);      // 2,097,152 B
  int*   idxbuf = (int*)  (ws + 6307840);      //   131,072 B
  int*   rstop  = (int*)  (ws + 6438912);      //    16,384 B
  float* accs   = (float*)(ws + 6455296);      //    65,536 B
  int*   maxr   = (int*)  (ws + 6520832);      //       128 B

  float* out = (float*)d_out;
  float* out_stats = out + 16777216;           // B*T*V
  float* out_mem   = out + 16777221;           // + 5 stats

  k_pack <<<dim3(256), dim3(256), 0, stream>>>(vq_emb, vqT);
  k_vqsq <<<dim3(16),  dim3(256), 0, stream>>>(vq_emb, vqsq);
  k_recur<<<dim3(BB),  dim3(NT),  0, stream>>>(
      x_seq, enc_emb, vq_emb, vqT, vqsq,
      nrg, nrb, nig, nib, proj_w, proj_b, mgw, mgb, arb_w, arb_b, hb, ig,
      gwout, idxbuf, rstop, accs, out_mem);
  k_dec  <<<dim3(16, 128), dim3(256), 0, stream>>>(gwout, dec_w, dec_b, out);
  k_max  <<<dim3(1),   dim3(256), 0, stream>>>(rstop, maxr, out_stats);
  k_tail <<<dim3(BB * TT), dim3(256), 0, stream>>>(vqT, vqsq, gwout, rstop, maxr, idxbuf,
                                                   nrg, nrb, nig, nib);
  k_stats<<<dim3(TT),  dim3(512), 0, stream>>>(idxbuf, rstop, accs, maxr, out_stats);
}

// Round 11
// 634.798 us; speedup vs baseline: 3.0883x; 3.0883x over previous
//
#include <hip/hip_runtime.h>
#include <math.h>

#define BB 128
#define TT 32
#define DDIM 64
#define VV 4096
#define SS 32
#define RR 8
#define NT 512
#define SMP 65   // padded leading dim for s_mem

typedef unsigned short u16;
typedef unsigned int u32;
typedef _Float16 h2 __attribute__((ext_vector_type(2)));

__device__ __forceinline__ h2 bch(u32 u){ union { u32 u; h2 h; } v; v.u = u; return v.h; }

__device__ __forceinline__ float fdot2f(u32 a, u32 b, float acc){
#if __has_builtin(__builtin_amdgcn_fdot2)
  return __builtin_amdgcn_fdot2(bch(a), bch(b), acc, false);
#else
  h2 x = bch(a), y = bch(b);
  return acc + (float)x[0] * (float)y[0] + (float)x[1] * (float)y[1];
#endif
}

__device__ __forceinline__ u32 packh2(float a, float b){
  union { _Float16 h[2]; u32 u; } p;
  p.h[0] = (_Float16)a; p.h[1] = (_Float16)b;
  return p.u;
}

__device__ __forceinline__ void bar(){ __syncthreads(); }

// ---------------- K0a: pack vq_emb into lane-coalesced f16 tiles ----------------
// vqT uint4 index: ((c0*16 + dc8)*64 + l), code c = c0*64+l, dims dc8*8..dc8*8+7 (8 f16)
// float4 loads; pack order identical to scalar version (bit-identical output).
__global__ __launch_bounds__(256) void k_pack(const float* __restrict__ vq, u32* __restrict__ vqT){
  int gid = blockIdx.x * 256 + threadIdx.x;     // 65536 entries
  int l   = gid & 63;
  int dc8 = (gid >> 6) & 15;
  int c0  = gid >> 10;
  int c   = (c0 << 6) + l;
  const float4* s4 = (const float4*)(vq + c * 128 + dc8 * 8);  // 32B-aligned
  float4 lo = s4[0], hi = s4[1];
  uint4 o;
  o.x = packh2(lo.x, lo.y);
  o.y = packh2(lo.z, lo.w);
  o.z = packh2(hi.x, hi.y);
  o.w = packh2(hi.z, hi.w);
  ((uint4*)vqT)[gid] = o;
}

// ---------------- K0b: per-code squared norm (exact f32) ----------------
// float4 loads; fmaf accumulation order identical to the scalar loop (bit-identical).
__global__ __launch_bounds__(256) void k_vqsq(const float* __restrict__ vq, float* __restrict__ vqsq){
  int c = blockIdx.x * 256 + threadIdx.x;
  const float4* v4 = (const float4*)(vq + c * 128);
  float s = 0.f;
  #pragma unroll
  for (int d = 0; d < 32; d++){
    float4 v = v4[d];
    s = fmaf(v.x, v.x, s); s = fmaf(v.y, v.y, s);
    s = fmaf(v.z, v.z, s); s = fmaf(v.w, v.w, s);
  }
  vqsq[c] = s;
}

// ---------------- K1: the full recurrence, one block per batch row ----------------
// R11 = R5's k_recur verbatim (best harness-verified: 450us, total 639us).
// Register-level VQ double-buffering is permanently abandoned: 5 attempts
// (R2/R6/R7/R9/R10) all spill — this toolchain caps the kernel at 128 VGPRs
// under every launch_bounds configuration tried.
__global__ __launch_bounds__(NT) void k_recur(
    const int* __restrict__ x_seq, const float* __restrict__ enc_emb,
    const float* __restrict__ vq_emb, const u32* __restrict__ vqT,
    const float* __restrict__ vq_sq,
    const float* __restrict__ nrg, const float* __restrict__ nrb,
    const float* __restrict__ nig, const float* __restrict__ nib,
    const float* __restrict__ proj_w, const float* __restrict__ proj_b,
    const float* __restrict__ mgw, const float* __restrict__ mgb,
    const float* __restrict__ arb_w, const float* __restrict__ arb_b,
    const float* __restrict__ hb, const float* __restrict__ ig,
    float* __restrict__ gwout,
    int* __restrict__ idxbuf, int* __restrict__ rstop_g, float* __restrict__ accs,
    float* __restrict__ out_mem)
{
  const int b = blockIdx.x;
  const int tid = threadIdx.x;
  const int lane = tid & 63;
  const int wave = tid >> 6;

  __shared__ __align__(16) float s_gw[128];     // state (own-element updates only)
  __shared__ __align__(16) float s_flat[128];
  __shared__ __align__(16) u32   s_flath[64];   // f16 copy of s_flat (64 half2)
  __shared__ __align__(16) float s_c[128];      // committed state copy (stable for PH / wg)
  __shared__ __align__(16) float s_zq[128];     // selected code row (wave 1, MV phase)
  __shared__ __align__(16) float s_enext[128];  // next-t embedding row (wave 3, MV r=0)
  __shared__ float s_mem[2][SS][SMP];           // padded: no stride-64 conflicts
  __shared__ __align__(16) float s_mv[12][DDIM];// s_mv[2*w2+half]: xhalf @ W(p,wsel)
  __shared__ float s_sim[SS];
  __shared__ float s_red[8];                    // 0: vq_loss, 4..6: arb logits
  __shared__ float s_cand[8];
  __shared__ int   s_candi[8];

  for (int i = tid; i < 128; i += NT) s_gw[i] = 0.f;
  for (int i = tid; i < 2 * SS * SMP; i += NT) ((float*)s_mem)[i] = 0.f;
  // first embedding row staged before the loop
  if (tid < 128) s_enext[tid] = enc_emb[x_seq[b * TT] * 128 + tid];
  __syncthreads();

  const float alpha = 1.f / (1.f + expf(-ig[0]));
  float bias_h; { float x = hb[0]; bias_h = log1pf(expf(x)); }
  int head = 0;
  float prev_ang = 0.f;   // wave 2 only
  float acc_ph = 0.f;     // wave 2 only

  // per-lane proj_b preloads (layout (3,2,64)): [(p*2+ri)*64 + lane]
  const float pb0r = proj_b[lane],        pb0i = proj_b[64 + lane];
  const float pb1r = proj_b[128 + lane],  pb1i = proj_b[192 + lane];
  const float pb2r = proj_b[256 + lane],  pb2i = proj_b[320 + lane];

  const uint4* vqT4 = (const uint4*)vqT;

  #pragma unroll 1
  for (int t = 0; t < TT; t++){
    // ---- E: embedding blend from staged row (own elements only)
    if (tid < 128){
      s_gw[tid] = alpha * s_gw[tid] + (1.f - alpha) * s_enext[tid];
    }
    bar();                                  // B0: s_gw blended, visible
    if (wave == 2) prev_ang = atan2f(s_gw[64 + lane], s_gw[lane]);

    float vl_last = 0.f;
    if (wave == 2) acc_ph = 0.f;
    int rst = 0;
    bool stop = false;

    #pragma unroll 1
    for (int r = 0; r < RR; r++){
      // ---- LN halves -> s_flat (f32) + s_flath (f16 pairs)  [waves 0,1]
      if (wave < 2){
        float x = s_gw[wave * 64 + lane];   // own element (written by this thread)
        float mu = x;
        #pragma unroll
        for (int m = 1; m < 64; m <<= 1) mu += __shfl_xor(mu, m);
        mu *= (1.f / 64.f);
        float dxl = x - mu;
        float vv = dxl * dxl;
        #pragma unroll
        for (int m = 1; m < 64; m <<= 1) vv += __shfl_xor(vv, m);
        vv *= (1.f / 64.f);
        float rs = 1.f / sqrtf(vv + 1e-5f);
        const float* g  = wave ? nig : nrg;
        const float* bb = wave ? nib : nrb;
        float fv = dxl * rs * g[lane] + bb[lane];
        s_flat[wave * 64 + lane] = fv;
        float pv = __shfl_xor(fv, 1);
        if ((lane & 1) == 0)
          s_flath[(wave * 64 + lane) >> 1] = packh2(fv, pv);
      }
      bar();                                // B1: flat ready

      // ---- VQ nearest-code search: f16 dots (4 accumulators), f32 norms hoisted
      //      before the load burst; register-lean single U buffer (v42-proven).
      uint4 F[16];
      {
        const uint4* sfh4 = (const uint4*)s_flath;
        #pragma unroll
        for (int i = 0; i < 16; i++) F[i] = sfh4[i];
      }
      float bsc = 3.4e38f; int bidx = 0;
      #pragma unroll 1
      for (int k = 0; k < 8; k++){
        int c0 = wave + 8 * k;
        int c  = (c0 << 6) + lane;
        float qv = vq_sq[c];                // issued before the U burst; hides under it
        const uint4* vp = vqT4 + (c0 * 16) * 64 + lane;
        uint4 U[16];
        #pragma unroll
        for (int dc8 = 0; dc8 < 16; dc8++) U[dc8] = vp[dc8 * 64];
        float a0 = 0.f, a1 = 0.f, a2 = 0.f, a3 = 0.f;
        #pragma unroll
        for (int dc8 = 0; dc8 < 16; dc8 += 4){
          a0 = fdot2f(U[dc8+0].x, F[dc8+0].x, a0); a0 = fdot2f(U[dc8+0].y, F[dc8+0].y, a0);
          a0 = fdot2f(U[dc8+0].z, F[dc8+0].z, a0); a0 = fdot2f(U[dc8+0].w, F[dc8+0].w, a0);
          a1 = fdot2f(U[dc8+1].x, F[dc8+1].x, a1); a1 = fdot2f(U[dc8+1].y, F[dc8+1].y, a1);
          a1 = fdot2f(U[dc8+1].z, F[dc8+1].z, a1); a1 = fdot2f(U[dc8+1].w, F[dc8+1].w, a1);
          a2 = fdot2f(U[dc8+2].x, F[dc8+2].x, a2); a2 = fdot2f(U[dc8+2].y, F[dc8+2].y, a2);
          a2 = fdot2f(U[dc8+2].z, F[dc8+2].z, a2); a2 = fdot2f(U[dc8+2].w, F[dc8+2].w, a2);
          a3 = fdot2f(U[dc8+3].x, F[dc8+3].x, a3); a3 = fdot2f(U[dc8+3].y, F[dc8+3].y, a3);
          a3 = fdot2f(U[dc8+3].z, F[dc8+3].z, a3); a3 = fdot2f(U[dc8+3].w, F[dc8+3].w, a3);
        }
        float dot = (a0 + a1) + (a2 + a3);
        float sc = qv - 2.f * dot;
        if (sc < bsc || (sc == bsc && c < bidx)){ bsc = sc; bidx = c; }
      }
      #pragma unroll
      for (int m = 1; m < 64; m <<= 1){
        float os = __shfl_xor(bsc, m);
        int   oi = __shfl_xor(bidx, m);
        if (os < bsc || (os == bsc && oi < bidx)){ bsc = os; bidx = oi; }
      }
      if (lane == 0){ s_cand[wave] = bsc; s_candi[wave] = bidx; }
      bar();                                // B2: candidates ready

      // ---- MV phase: role-split.
      //   waves 2..7: one proj_w matrix each, BOTH x-half dots (halves W traffic)
      //   wave 3 additionally stages next-t enc row at r==0
      //   wave 0: sim + softmax
      //   wave 1: imin reduce + arb + vq_loss + zq stash + idx write
      if (wave >= 2){
        if (wave == 3 && r == 0 && t + 1 < TT){
          int xn = x_seq[b * TT + t + 1];
          s_enext[lane]      = enc_emb[xn * 128 + lane];
          s_enext[64 + lane] = enc_emb[xn * 128 + 64 + lane];
        }
        const int w2 = wave - 2;            // 0..5 -> (p, wsel)
        const int p = w2 >> 1, wsel = w2 & 1;
        const float* W = proj_w + ((p * 2 + wsel) << 12);
        float a0=0.f,a1=0.f,a2=0.f,a3=0.f;  // x_low (dims 0..63)
        float b0=0.f,b1=0.f,b2=0.f,b3=0.f;  // x_high (dims 64..127)
        #pragma unroll
        for (int i = 0; i < 64; i += 4){
          float4 xr4 = *(const float4*)&s_flat[i];
          float4 xi4 = *(const float4*)&s_flat[64 + i];
          float w0 = W[(i + 0) * 64 + lane];
          float w1 = W[(i + 1) * 64 + lane];
          float w2v= W[(i + 2) * 64 + lane];
          float w3 = W[(i + 3) * 64 + lane];
          a0 = fmaf(xr4.x, w0, a0); a1 = fmaf(xr4.y, w1, a1);
          a2 = fmaf(xr4.z, w2v, a2); a3 = fmaf(xr4.w, w3, a3);
          b0 = fmaf(xi4.x, w0, b0); b1 = fmaf(xi4.y, w1, b1);
          b2 = fmaf(xi4.z, w2v, b2); b3 = fmaf(xi4.w, w3, b3);
        }
        s_mv[w2 * 2 + 0][lane] = (a0 + a1) + (a2 + a3);   // x_low  @ W
        s_mv[w2 * 2 + 1][lane] = (b0 + b1) + (b2 + b3);   // x_high @ W
      } else if (wave == 0){
        // sim over 32 slots (lane<32: dims 0-63, lane>=32: dims 64-127) + softmax
        const int s2 = lane & 31, h = lane >> 5;
        const float* mrow = &s_mem[h][s2][0];
        const float* fx = s_flat + h * 64;
        float a0=0.f,a1=0.f,a2=0.f,a3=0.f;
        #pragma unroll
        for (int d = 0; d < 64; d += 4){
          a0 = fmaf(mrow[d + 0], fx[d + 0], a0);
          a1 = fmaf(mrow[d + 1], fx[d + 1], a1);
          a2 = fmaf(mrow[d + 2], fx[d + 2], a2);
          a3 = fmaf(mrow[d + 3], fx[d + 3], a3);
        }
        float p = (a0 + a1) + (a2 + a3);
        p += __shfl_xor(p, 32);             // full 128-dim sim, dup in both halves
        float mx = p;
        #pragma unroll
        for (int m = 1; m < 32; m <<= 1) mx = fmaxf(mx, __shfl_xor(mx, m));
        float e = expf(p - mx);
        float sm = e;
        #pragma unroll
        for (int m = 1; m < 32; m <<= 1) sm += __shfl_xor(sm, m);
        if (lane < 32) s_sim[lane] = e / sm;
      } else {
        // wave 1: imin reduce + arbiter logits + vq_loss + zq stash + idx write
        float bs = s_cand[0]; int bi = s_candi[0];
        #pragma unroll
        for (int w = 1; w < 8; w++){
          float os = s_cand[w]; int oi = s_candi[w];
          if (os < bs || (os == bs && oi < bi)){ bs = os; bi = oi; }
        }
        int imin = __builtin_amdgcn_readfirstlane(bi);
        float f0 = s_flat[lane], f1 = s_flat[64 + lane];
        float p0 = fmaf(f0, arb_w[lane * 3 + 0], f1 * arb_w[(64 + lane) * 3 + 0]);
        float p1 = fmaf(f0, arb_w[lane * 3 + 1], f1 * arb_w[(64 + lane) * 3 + 1]);
        float p2 = fmaf(f0, arb_w[lane * 3 + 2], f1 * arb_w[(64 + lane) * 3 + 2]);
        float z0 = vq_emb[imin * 128 + lane];
        float z1 = vq_emb[imin * 128 + 64 + lane];
        s_zq[lane]      = z0;
        s_zq[64 + lane] = z1;
        float d0 = z0 - f0, d1 = z1 - f1;
        float sq = d0 * d0 + d1 * d1;
        #pragma unroll
        for (int m = 1; m < 64; m <<= 1){
          p0 += __shfl_xor(p0, m); p1 += __shfl_xor(p1, m);
          p2 += __shfl_xor(p2, m); sq += __shfl_xor(sq, m);
        }
        if (lane == 0){
          s_red[4] = p0 + arb_b[0];
          s_red[5] = p1 + arb_b[1];
          s_red[6] = p2 + arb_b[2];
          s_red[0] = 1.25f * sq * (1.f / 128.f);
          idxbuf[(b * TT + t) * RR + r] = imin;
        }
      }
      bar();                                // B3: mv, sim, arb, vq_loss, zq ready

      float vl = s_red[0];
      stop = (bias_h - vl) > 0.f;           // bit-identical in every thread -> uniform
      vl_last = vl; rst = r;

      // ---- CAND: per-lane q/k/w combine, gate reduce, memory read, gates softmax,
      //      candidate, commit
      if (tid < 128){
        float qr = s_mv[0][lane] - s_mv[3][lane] + pb0r - pb0i;
        float qi = s_mv[1][lane] + s_mv[2][lane] + pb0r + pb0i;
        float kr = s_mv[4][lane] - s_mv[7][lane] + pb1r - pb1i;
        float ki = s_mv[5][lane] + s_mv[6][lane] + pb1r + pb1i;
        float g = fmaf(qr, kr, qi * ki);
        #pragma unroll
        for (int m = 1; m < 64; m <<= 1) g += __shfl_xor(g, m);
        float gate = 1.f / (1.f + expf(-g));
        const int h = wave, j = lane;
        float m_reg = 0.f;
        #pragma unroll 8
        for (int s2 = 0; s2 < 32; s2++)
          m_reg = fmaf(s_sim[s2], s_mem[h][s2][j], m_reg);
        float l0 = s_red[4], l1 = s_red[5], l2 = s_red[6];
        float mx = fmaxf(l0, fmaxf(l1, l2));
        float e0 = expf(l0 - mx), e1 = expf(l1 - mx), e2 = expf(l2 - mx);
        float inv = 1.f / (e0 + e1 + e2);
        float zq = s_zq[tid];               // LDS (stashed by wave 1 in MV)
        float wv = h ? (s_mv[9][j] + s_mv[10][j] + pb2r + pb2i)
                     : (s_mv[8][j] - s_mv[11][j] + pb2r - pb2i);
        float u = (e0 * inv) * (gate * wv) + (e1 * inv) * m_reg + (e2 * inv) * zq;
        float cv = 0.6f * s_flat[tid] + 0.4f * u;
        s_c[tid]  = cv;       // stable copy for PH / wg readers
        s_gw[tid] = cv;       // state commit
      }
      bar();                                // B4: s_c ready

      // ---- PH: phase difference (wave 2 — does not serialize with next-r LN)
      if (wave == 2){
        float ang = atan2f(s_c[64 + lane], s_c[lane]);
        float df = fabsf(ang - prev_ang);
        df = fminf(df, 6.28318530717958647692f - df);
        prev_ang = ang;
        #pragma unroll
        for (int m = 1; m < 64; m <<= 1) df += __shfl_xor(df, m);
        acc_ph += df * (1.f / 64.f);
        if ((stop || r == RR - 1) && lane == 0)
          accs[(b * TT + t) * 4 + 2] = acc_ph;
      }
      if (stop) break;
    } // r

    // ---- post-t: output, memory-gate (redundant in waves 0,1), memory update
    float pond = 0.01f * (float)(rst + 1);
    if (tid < 128) gwout[(b * TT + t) * 128 + tid] = s_gw[tid];   // own value
    head = (head + SS - 1) & (SS - 1);
    if (wave < 2){
      float p = fmaf(s_c[lane], mgw[lane], s_c[64 + lane] * mgw[64 + lane]);
      #pragma unroll
      for (int m = 1; m < 64; m <<= 1) p += __shfl_xor(p, m);
      float wg = 1.f / (1.f + expf(-(p + mgb[0])));
      const int h = wave, d0 = lane;
      float old = s_mem[h][head][d0];
      s_mem[h][head][d0] = wg * s_c[h * 64 + d0] + (1.f - wg) * old;
    }
    if (tid == 0){
      int o = b * TT + t;
      rstop_g[o] = rst;
      accs[o * 4 + 0] = vl_last;
      accs[o * 4 + 1] = pond;
    }
    // ordering to next t: s_gw/E own-element; s_enext write (wave3, MV r=0) vs E read
    // separated by B0..B2; s_c next write after next B3; s_mem next read after next B2.
  } // t

  bar();
  for (int i = tid; i < SS * DDIM; i += NT){
    int s2 = i >> 6, d0 = i & 63;
    int ph = (head + s2) & (SS - 1);
    out_mem[b * SS * DDIM + i] = s_mem[0][ph][d0];
    out_mem[BB * SS * DDIM + b * SS * DDIM + i] = s_mem[1][ph][d0];
  }
}

// ---------------- Kmax: per-timestep max r_stop + zero stats accumulators ----------------
__global__ __launch_bounds__(256) void k_max(const int* __restrict__ rstop_g,
                                             int* __restrict__ maxr,
                                             float* __restrict__ out_stats){
  __shared__ int sm[8][TT];
  int tid = threadIdx.x;
  int t = tid & 31, q = tid >> 5;           // 8 groups x 16 b's each
  int mx = 0;
  for (int b = q * 16; b < q * 16 + 16; b++) mx = max(mx, rstop_g[b * TT + t]);
  sm[q][t] = mx;
  __syncthreads();
  if (tid < TT){
    int m = sm[0][tid];
    #pragma unroll
    for (int qq = 1; qq < 8; qq++) m = max(m, sm[qq][tid]);
    maxr[tid] = m;
  } else if (tid >= 64 && tid < 69){
    out_stats[tid - 64] = 0.f;              // zeroed every launch, before k_stats
  }
}

// ---------------- K1b: fill frozen tail idx (cold path) ----------------
// Recomputes LN(gwout) with the identical shuffle sequence the hot path uses.
__global__ __launch_bounds__(256) void k_tail(
    const u32* __restrict__ vqT, const float* __restrict__ vq_sq,
    const float* __restrict__ gwout, const int* __restrict__ rstop_g,
    const int* __restrict__ maxr, int* __restrict__ idxbuf,
    const float* __restrict__ nrg, const float* __restrict__ nrb,
    const float* __restrict__ nig, const float* __restrict__ nib)
{
  int o = blockIdx.x;               // b*TT + t
  int t = o & (TT - 1);
  int rs = rstop_g[o];
  if (rs >= maxr[t]) return;
  __shared__ __align__(16) u32 sfh[64];
  __shared__ float s_cand[4];
  __shared__ int   s_candi[4];
  int tid = threadIdx.x, lane = tid & 63, wave = tid >> 6;
  if (wave < 2){
    float x = gwout[o * 128 + wave * 64 + lane];
    float mu = x;
    #pragma unroll
    for (int m = 1; m < 64; m <<= 1) mu += __shfl_xor(mu, m);
    mu *= (1.f / 64.f);
    float dxl = x - mu;
    float vv = dxl * dxl;
    #pragma unroll
    for (int m = 1; m < 64; m <<= 1) vv += __shfl_xor(vv, m);
    vv *= (1.f / 64.f);
    float rsn = 1.f / sqrtf(vv + 1e-5f);
    const float* g  = wave ? nig : nrg;
    const float* bb = wave ? nib : nrb;
    float fv = dxl * rsn * g[lane] + bb[lane];
    float pv = __shfl_xor(fv, 1);
    if ((lane & 1) == 0) sfh[(wave * 64 + lane) >> 1] = packh2(fv, pv);
  }
  __syncthreads();
  uint4 F[16];
  {
    const uint4* sfh4 = (const uint4*)sfh;
    #pragma unroll
    for (int i = 0; i < 16; i++) F[i] = sfh4[i];
  }
  float bsc = 3.4e38f; int bidx = 0;
  #pragma unroll 1
  for (int k = 0; k < 16; k++){
    int c0 = wave + 4 * k;
    const uint4* vp = ((const uint4*)vqT) + (c0 * 16) * 64 + lane;
    uint4 U[16];
    #pragma unroll
    for (int dc8 = 0; dc8 < 16; dc8++) U[dc8] = vp[dc8 * 64];
    float dot = 0.f;
    #pragma unroll
    for (int dc8 = 0; dc8 < 16; dc8++){
      dot = fdot2f(U[dc8].x, F[dc8].x, dot);
      dot = fdot2f(U[dc8].y, F[dc8].y, dot);
      dot = fdot2f(U[dc8].z, F[dc8].z, dot);
      dot = fdot2f(U[dc8].w, F[dc8].w, dot);
    }
    int c = c0 * 64 + lane;
    float sc = vq_sq[c] - 2.f * dot;
    if (sc < bsc || (sc == bsc && c < bidx)){ bsc = sc; bidx = c; }
  }
  #pragma unroll
  for (int m = 1; m < 64; m <<= 1){
    float os = __shfl_xor(bsc, m);
    int   oi = __shfl_xor(bidx, m);
    if (os < bsc || (os == bsc && oi < bidx)){ bsc = os; bidx = oi; }
  }
  if (lane == 0){ s_cand[wave] = bsc; s_candi[wave] = bidx; }
  __syncthreads();
  if (tid == 0){
    float bs = s_cand[0]; int bi = s_candi[0];
    for (int w = 1; w < 4; w++){
      float os = s_cand[w]; int oi = s_candi[w];
      if (os < bs || (os == bs && oi < bi)){ bs = os; bi = oi; }
    }
    for (int r = rs + 1; r < RR; r++) idxbuf[o * RR + r] = bi;
  }
}

// ---------------- K2: entropy/perplexity + final stats (32 blocks, one per t) ----------------
// out_stats zeroed by k_max (stream-ordered earlier); partial means accumulated
// via atomicAdd (f32 reorder error ~1e-7, far under tolerance).
__global__ __launch_bounds__(512) void k_stats(
    const int* __restrict__ idxbuf, const int* __restrict__ rstop_g,
    const float* __restrict__ accs, const int* __restrict__ maxr,
    float* __restrict__ out_stats)
{
  __shared__ int   s_vals[8][128];
  __shared__ float s_ent2[RR];
  __shared__ float s_part[8][5];
  const int t = blockIdx.x;
  int tid = threadIdx.x, lane = tid & 63, wave = tid >> 6;
  int mr = maxr[t];
  int r = wave;                       // 8 waves <-> 8 r's
  if (r <= mr){
    int v1 = idxbuf[(lane * TT + t) * RR + r];
    int v2 = idxbuf[((64 + lane) * TT + t) * RR + r];
    s_vals[wave][lane]      = v1;
    s_vals[wave][64 + lane] = v2;     // same-wave LDS RAW: ordered by lgkmcnt
    int c1 = 0, c2 = 0;
    for (int j = 0; j < 128; j++){
      int v = s_vals[wave][j];
      c1 += (v == v1); c2 += (v == v2);
    }
    float contrib = -(logf((float)c1 * (1.f / 128.f) + 1e-10f)
                    + logf((float)c2 * (1.f / 128.f) + 1e-10f)) * (1.f / 128.f);
    #pragma unroll
    for (int m = 1; m < 64; m <<= 1) contrib += __shfl_xor(contrib, m);
    if (lane == 0) s_ent2[r] = contrib;
  }
  __syncthreads();

  float sv = 0.f, sp = 0.f, se = 0.f, sn = 0.f, sh = 0.f;
  if (tid < BB){
    int o = tid * TT + t;             // one b per thread
    int rs = rstop_g[o];
    float ent = s_ent2[rs];
    se = ent;
    sp = expf(ent);
    sv = accs[o * 4 + 0];
    sn = accs[o * 4 + 1];
    sh = accs[o * 4 + 2];
  }
  #pragma unroll
  for (int m = 1; m < 64; m <<= 1){
    sv += __shfl_xor(sv, m); sp += __shfl_xor(sp, m); se += __shfl_xor(se, m);
    sn += __shfl_xor(sn, m); sh += __shfl_xor(sh, m);
  }
  if (lane == 0){
    s_part[wave][0] = sv; s_part[wave][1] = sp; s_part[wave][2] = se;
    s_part[wave][3] = sn; s_part[wave][4] = sh;
  }
  __syncthreads();
  if (tid == 0){
    float a[5] = {0.f, 0.f, 0.f, 0.f, 0.f};
    for (int w = 0; w < 8; w++)
      for (int j = 0; j < 5; j++) a[j] += s_part[w][j];
    const float inv = 1.f / (float)(BB * TT);
    for (int j = 0; j < 5; j++) atomicAdd(&out_stats[j], a[j] * inv);
  }
}

// ---------------- K3: decoder GEMM  logits = flat_out @ dec_w + dec_b ----------------
__global__ __launch_bounds__(256) void k_dec(
    const float* __restrict__ gwout, const float* __restrict__ dec_w,
    const float* __restrict__ dec_b, float* __restrict__ out)
{
  __shared__ float At[32][128];
  int tid = threadIdx.x;
  int row0 = blockIdx.y * 32;
  int col0 = blockIdx.x * 256;
  {
    const float4* src = (const float4*)(gwout + row0 * 128);
    float4* dst = (float4*)&At[0][0];
    for (int i = tid; i < 1024; i += 256) dst[i] = src[i];
  }
  __syncthreads();
  int v = col0 + tid;
  float acc[32];
  #pragma unroll
  for (int r2 = 0; r2 < 32; r2++) acc[r2] = 0.f;
  for (int k = 0; k < 128; k += 4){
    float w0 = dec_w[(k + 0) * 4096 + v];
    float w1 = dec_w[(k + 1) * 4096 + v];
    float w2 = dec_w[(k + 2) * 4096 + v];
    float w3 = dec_w[(k + 3) * 4096 + v];
    #pragma unroll
    for (int r2 = 0; r2 < 32; r2++){
      float4 a = *(const float4*)&At[r2][k];
      acc[r2] = fmaf(a.x, w0, fmaf(a.y, w1, fmaf(a.z, w2, fmaf(a.w, w3, acc[r2]))));
    }
  }
  float bv = dec_b[v];
  for (int r2 = 0; r2 < 32; r2++)
    out[(row0 + r2) * 4096 + v] = acc[r2] + bv;
}

extern "C" void kernel_launch(void* const* d_in, const int* in_sizes, int n_in,
                              void* d_out, int out_size, void* d_ws, size_t ws_size,
                              hipStream_t stream){
  const int*   x_seq   = (const int*)  d_in[0];
  const float* enc_emb = (const float*)d_in[1];
  const float* vq_emb  = (const float*)d_in[2];
  const float* nrg     = (const float*)d_in[3];
  const float* nrb     = (const float*)d_in[4];
  const float* nig     = (const float*)d_in[5];
  const float* nib     = (const float*)d_in[6];
  const float* proj_w  = (const float*)d_in[7];
  const float* proj_b  = (const float*)d_in[8];
  const float* mgw     = (const float*)d_in[9];
  const float* mgb     = (const float*)d_in[10];
  const float* arb_w   = (const float*)d_in[11];
  const float* arb_b   = (const float*)d_in[12];
  const float* dec_w   = (const float*)d_in[13];
  const float* dec_b   = (const float*)d_in[14];
  const float* hb      = (const float*)d_in[15];
  const float* ig      = (const float*)d_in[16];

  char* ws = (char*)d_ws;
  u32*   vqT    = (u32*)  (ws + 0);            // 1,048,576 B (f16 tiles)
  float* vqsq   = (float*)(ws + 2097152);      //    16,384 B
  float* gwout  = (float*)(ws + 2113536);      // 2,097,152 B
  int*   idxbuf = (int*)  (ws + 6307840);      //   131,072 B
  int*   rstop  = (int*)  (ws + 6438912);      //    16,384 B
  float* accs   = (float*)(ws + 6455296);      //    65,536 B
  int*   maxr   = (int*)  (ws + 6520832);      //       128 B

  float* out = (float*)d_out;
  float* out_stats = out + 16777216;           // B*T*V
  float* out_mem   = out + 16777221;           // + 5 stats

  k_pack <<<dim3(256), dim3(256), 0, stream>>>(vq_emb, vqT);
  k_vqsq <<<dim3(16),  dim3(256), 0, stream>>>(vq_emb, vqsq);
  k_recur<<<dim3(BB),  dim3(NT),  0, stream>>>(
      x_seq, enc_emb, vq_emb, vqT, vqsq,
      nrg, nrb, nig, nib, proj_w, proj_b, mgw, mgb, arb_w, arb_b, hb, ig,
      gwout, idxbuf, rstop, accs, out_mem);
  k_dec  <<<dim3(16, 128), dim3(256), 0, stream>>>(gwout, dec_w, dec_b, out);
  k_max  <<<dim3(1),   dim3(256), 0, stream>>>(rstop, maxr, out_stats);
  k_tail <<<dim3(BB * TT), dim3(256), 0, stream>>>(vqT, vqsq, gwout, rstop, maxr, idxbuf,
                                                   nrg, nrb, nig, nib);
  k_stats<<<dim3(TT),  dim3(512), 0, stream>>>(idxbuf, rstop, accs, maxr, out_stats);
}